// Round 2
// baseline (5348.121 us; speedup 1.0000x reference)
//
#include <hip/hip_runtime.h>
#include <hip/hip_bf16.h>

#define B_   32
#define T_   512
#define E_   300
#define H_   256
#define G4_  1024
#define OUT_ 256
#define EPAD 304   // LDS pad for emb rows
#define HPAD 260   // LDS pad for h rows

// ---------------------------------------------------------------------------
// Slot tables: fslot[b][t] = index among True fmask positions (else -1)
//              bpos [b][t] = OUT-1-index among True bmask positions (else -1)
// Runtime-detects whether masks arrived as 1-byte bool or int32:
// per-row nonzero-byte count over 512 bytes is exactly 256 iff bool
// (masks have exactly 256 True per row), and <=128 iff int32.
// ---------------------------------------------------------------------------
__global__ __launch_bounds__(64) void slots_kernel(
    const unsigned char* __restrict__ fm, const unsigned char* __restrict__ bm,
    int* __restrict__ fslot, int* __restrict__ bpos)
{
    int b = threadIdx.x;
    if (b >= B_) return;
    int cnt = 0;
    for (int t = 0; t < T_; ++t) cnt += (fm[b * T_ + t] != 0);
    bool isbool = (cnt == 256);
    const int* fmi = (const int*)fm;
    const int* bmi = (const int*)bm;
    int jf = 0, jb = 0;
    for (int t = 0; t < T_; ++t) {
        bool f = isbool ? (fm[b * T_ + t] != 0) : (fmi[b * T_ + t] != 0);
        bool g = isbool ? (bm[b * T_ + t] != 0) : (bmi[b * T_ + t] != 0);
        fslot[b * T_ + t] = f ? (jf++) : -1;
        bpos [b * T_ + t] = g ? (OUT_ - 1 - (jb++)) : -1;
    }
}

// ---------------------------------------------------------------------------
// xg GEMM: xg[dir][tc][row][b] = dot(emb[token(dir,b,t)], W_ih[dir][row]) + b_ih + b_hh
// token: dir0 -> inputs[b][t]; dir1 -> inputs[b][L-1-t] if t<L else inputs[b][t]
// grid (16 row-blocks of 64, chunksize, 2 dirs), block 256
// ---------------------------------------------------------------------------
__global__ __launch_bounds__(256) void xg_gemm(
    const int* __restrict__ inputs, const int* __restrict__ seqlen,
    const float* __restrict__ emb,
    const float* __restrict__ Wihf, const float* __restrict__ Wihb,
    const float* __restrict__ bihf, const float* __restrict__ bhhf,
    const float* __restrict__ bihb, const float* __restrict__ bhhb,
    float* __restrict__ xg, int t0, int TcMax)
{
    const int tc  = blockIdx.y;
    const int t   = t0 + tc;
    const int dir = blockIdx.z;
    const int rblk = blockIdx.x * 64;

    __shared__ float eL[B_][EPAD];

    // stage 32 embedding rows (gathered) into LDS
    for (int idx = threadIdx.x; idx < B_ * 75; idx += 256) {
        int b = idx / 75, q = idx - b * 75;
        int L = seqlen[b];
        int tt = t;
        if (dir) tt = (t < L) ? (L - 1 - t) : t;
        int tok = inputs[b * T_ + tt];
        float4 v = *(const float4*)(emb + (size_t)tok * E_ + q * 4);
        *(float4*)(&eL[b][q * 4]) = v;
    }
    __syncthreads();

    const float* W  = dir ? Wihb : Wihf;
    const float* bi = dir ? bihb : bihf;
    const float* bh = dir ? bhhb : bhhf;

    const int b  = threadIdx.x & 31;
    const int r8 = threadIdx.x >> 5;   // [0,8): rows r8 + 8m
    float acc[8];
#pragma unroll
    for (int m = 0; m < 8; ++m) acc[m] = 0.f;

    for (int e = 0; e < E_; e += 4) {
        float4 h4 = *(const float4*)(&eL[b][e]);
#pragma unroll
        for (int m = 0; m < 8; ++m) {
            int row = rblk + r8 + m * 8;
            float4 w4 = *(const float4*)(W + (size_t)row * E_ + e);
            acc[m] += h4.x * w4.x + h4.y * w4.y + h4.z * w4.z + h4.w * w4.w;
        }
    }

    float* outp = xg + ((size_t)dir * TcMax + tc) * (size_t)(G4_ * B_);
#pragma unroll
    for (int m = 0; m < 8; ++m) {
        int row = rblk + r8 + m * 8;
        outp[(size_t)row * B_ + b] = acc[m] + bi[row] + bh[row];
    }
}

// ---------------------------------------------------------------------------
// One LSTM time step for both directions.
// grid (64 unit-blocks of 4, 2 dirs), block 256.
// WG owns hidden units [u0, u0+4) -> 16 gate rows (lr = gate*4 + ul).
// h ping-pong in global ws (kernel boundary = device-wide visibility).
// Fused output scatter via slot tables.
// ---------------------------------------------------------------------------
__global__ __launch_bounds__(256) void lstm_step(
    const float* __restrict__ xg, const int* __restrict__ seqlen,
    const float* __restrict__ Whhf, const float* __restrict__ Whhb,
    const int* __restrict__ fslot, const int* __restrict__ bpos,
    float* __restrict__ h_ws, float* __restrict__ c_ws,
    float* __restrict__ out, int t, int tc, int TcMax)
{
    const int dir = blockIdx.y;
    const int u0  = blockIdx.x * 4;

    __shared__ float hL[B_][HPAD];
    __shared__ float gbuf[16][33];

    const float* hprev = h_ws + ((size_t)dir * 2 + (t & 1)) * (B_ * H_);
    float*       hnext = h_ws + ((size_t)dir * 2 + ((t & 1) ^ 1)) * (B_ * H_);

    // stage h(t-1) into LDS: [b][k]
    for (int idx = threadIdx.x; idx < B_ * (H_ / 4); idx += 256) {
        int b = idx >> 6, q = idx & 63;
        float4 v = *(const float4*)(hprev + b * H_ + q * 4);
        *(float4*)(&hL[b][q * 4]) = v;
    }
    __syncthreads();

    const float* W = dir ? Whhb : Whhf;
    const int b  = threadIdx.x & 31;
    const int r2 = threadIdx.x >> 5;          // [0,8): rows r2 and r2+8
    const int lr0 = r2, lr1 = r2 + 8;
    const int grow0 = (lr0 >> 2) * H_ + u0 + (lr0 & 3);
    const int grow1 = (lr1 >> 2) * H_ + u0 + (lr1 & 3);

    float a0 = 0.f, a1 = 0.f;
#pragma unroll 4
    for (int k = 0; k < H_; k += 4) {
        float4 h4 = *(const float4*)(&hL[b][k]);
        float4 w0 = *(const float4*)(W + (size_t)grow0 * H_ + k);
        float4 w1 = *(const float4*)(W + (size_t)grow1 * H_ + k);
        a0 += h4.x * w0.x + h4.y * w0.y + h4.z * w0.z + h4.w * w0.w;
        a1 += h4.x * w1.x + h4.y * w1.y + h4.z * w1.z + h4.w * w1.w;
    }

    const float* xgp = xg + ((size_t)dir * TcMax + tc) * (size_t)(G4_ * B_);
    gbuf[lr0][b] = a0 + xgp[(size_t)grow0 * B_ + b];
    gbuf[lr1][b] = a1 + xgp[(size_t)grow1 * B_ + b];
    __syncthreads();

    if (threadIdx.x < 128) {
        const int bb = threadIdx.x & 31;
        const int ul = threadIdx.x >> 5;     // [0,4)
        const int u  = u0 + ul;
        const int L  = seqlen[bb];
        float hold = hL[bb][u];
        float hnew;
        if (t < L) {
            float gi = gbuf[ul][bb];
            float gf = gbuf[4 + ul][bb];
            float gg = gbuf[8 + ul][bb];
            float go = gbuf[12 + ul][bb];
            float* cp = c_ws + ((size_t)dir * B_ + bb) * H_ + u;
            float c = *cp;
            float si = 1.f / (1.f + expf(-gi));
            float sf = 1.f / (1.f + expf(-gf));
            float so = 1.f / (1.f + expf(-go));
            c = sf * c + si * tanhf(gg);
            *cp = c;
            hnew = so * tanhf(c);
            if (dir == 0) {
                int j = fslot[bb * T_ + t];
                if (j >= 0) out[((size_t)bb * OUT_ + j) * 512 + u] = hnew;
            } else {
                int p = bpos[bb * T_ + t];
                if (p >= 0) out[((size_t)bb * OUT_ + p) * 512 + 256 + u] = hnew;
            }
        } else {
            hnew = hold;   // frozen beyond seq length (never selected)
        }
        hnext[bb * H_ + u] = hnew;
    }
}

// ---------------------------------------------------------------------------
extern "C" void kernel_launch(void* const* d_in, const int* in_sizes, int n_in,
                              void* d_out, int out_size, void* d_ws, size_t ws_size,
                              hipStream_t stream) {
    const int*           inputs = (const int*)d_in[0];
    const int*           seqlen = (const int*)d_in[1];
    const unsigned char* fm     = (const unsigned char*)d_in[2];
    const unsigned char* bm     = (const unsigned char*)d_in[3];
    // d_in[4] = out_seq_length (== 256, hardcoded)
    const float* emb  = (const float*)d_in[5];
    const float* Wihf = (const float*)d_in[6];
    const float* Whhf = (const float*)d_in[7];
    const float* bihf = (const float*)d_in[8];
    const float* bhhf = (const float*)d_in[9];
    const float* Wihb = (const float*)d_in[10];
    const float* Whhb = (const float*)d_in[11];
    const float* bihb = (const float*)d_in[12];
    const float* bhhb = (const float*)d_in[13];
    float* out = (float*)d_out;

    char* ws = (char*)d_ws;
    // ws layout (bytes):
    //   [0)        fslot int32[32][512]            65536
    //   [65536)    bpos  int32[32][512]            65536
    //   [131072)   h ping-pong f32[2][2][32][256]  262144
    //   [393216)   c f32[2][32][256]               131072
    //   [524288)   xg f32[2][TcMax][1024][32]      TcMax*262144
    int*   fslot = (int*)(ws);
    int*   bpos  = (int*)(ws + 65536);
    float* h_ws  = (float*)(ws + 131072);
    float* c_ws  = (float*)(ws + 393216);
    float* xg    = (float*)(ws + 524288);

    size_t avail = (ws_size > 524288) ? (ws_size - 524288) : 0;
    int TcMax = 1;
    for (int c = 128; c >= 1; c >>= 1) {
        if ((size_t)c * 262144 <= avail) { TcMax = c; break; }
    }

    // zero h ping-pong AND c each call — c is read-modify-write, and the
    // harness does not re-poison ws between timed replays (round-1 bug:
    // memset covered only h; c carried across replays -> revalidation fail).
    hipMemsetAsync(ws + 131072, 0, 524288 - 131072, stream);
    slots_kernel<<<1, 64, 0, stream>>>(fm, bm, fslot, bpos);

    for (int t0 = 0; t0 < T_; t0 += TcMax) {
        int cs = (T_ - t0 < TcMax) ? (T_ - t0) : TcMax;
        dim3 g(16, cs, 2);
        xg_gemm<<<g, 256, 0, stream>>>(inputs, seqlen, emb, Wihf, Wihb,
                                       bihf, bhhf, bihb, bhhb, xg, t0, TcMax);
        for (int tcc = 0; tcc < cs; ++tcc) {
            int t = t0 + tcc;
            lstm_step<<<dim3(64, 2), 256, 0, stream>>>(
                xg, seqlen, Whhf, Whhb, fslot, bpos, h_ws, c_ws, out, t, tcc, TcMax);
        }
    }
}